// Round 1
// baseline (546.614 us; speedup 1.0000x reference)
//
#include <hip/hip_runtime.h>
#include <stdint.h>

#define D_MEM 2048
#define BATCH 4096
#define K_DIM 4096   // 2*D
#define N_DIM 8192   // 4*D

typedef __bf16 bf16x8 __attribute__((ext_vector_type(8)));
typedef float f32x4 __attribute__((ext_vector_type(4)));

typedef const void __attribute__((address_space(1)))* gas_t;
typedef void __attribute__((address_space(3)))* las_t;

__device__ __forceinline__ ushort f2b(float f) {
  union { float f; uint32_t u; } v; v.f = f;
  uint32_t u = v.u + 0x7fffu + ((v.u >> 16) & 1u);
  return (ushort)(u >> 16);
}
__device__ __forceinline__ float b2f(ushort s) {
  union { uint32_t u; float f; } v; v.u = ((uint32_t)s) << 16;
  return v.f;
}
__device__ __forceinline__ float sigm(float x) {
  return 1.0f / (1.0f + __expf(-x));
}
__device__ __forceinline__ float tanh_fast(float x) {
  // tanh(x) = 2*sigmoid(2x) - 1 ; saturates correctly for |x| large
  return __builtin_fmaf(2.0f, sigm(2.0f * x), -1.0f);
}

// ---------------------------------------------------------------------------
// Kernel 1: cast+concat  A[m][k] = bf16( k<D ? lh[m][k] : rh[m][k-D] )
// ---------------------------------------------------------------------------
__global__ void cast_concat_kernel(const float* __restrict__ lh,
                                   const float* __restrict__ rh,
                                   ushort* __restrict__ A) {
  int i4 = blockIdx.x * 256 + threadIdx.x;     // 4096*1024 float4 groups
  int row = i4 >> 10;
  int col = (i4 & 1023) * 4;
  const float* src = (col < D_MEM) ? (lh + (size_t)row * D_MEM + col)
                                   : (rh + (size_t)row * D_MEM + (col - D_MEM));
  float4 v = *(const float4*)src;
  ushort4 o; o.x = f2b(v.x); o.y = f2b(v.y); o.z = f2b(v.z); o.w = f2b(v.w);
  *(ushort4*)(A + (size_t)row * K_DIM + col) = o;
}

// ---------------------------------------------------------------------------
// Kernel 2: transpose+cast  Bt[n][k] = bf16( W[k - koff][n] ),  W = Wl or Wr
// ---------------------------------------------------------------------------
__global__ void transpose_cast_kernel(const float* __restrict__ Wl,
                                      const float* __restrict__ Wr,
                                      ushort* __restrict__ Bt) {
  __shared__ float t[64 * 65];
  const float* W = blockIdx.z ? Wr : Wl;
  int n0 = blockIdx.x * 64;
  int k0 = blockIdx.y * 64;
  int tid = threadIdx.x;
#pragma unroll
  for (int i = 0; i < 4; ++i) {
    int idx = i * 256 + tid;
    int rr = idx >> 4;
    int c4 = (idx & 15) * 4;
    float4 v = *(const float4*)(W + (size_t)(k0 + rr) * N_DIM + n0 + c4);
    t[rr * 65 + c4 + 0] = v.x;
    t[rr * 65 + c4 + 1] = v.y;
    t[rr * 65 + c4 + 2] = v.z;
    t[rr * 65 + c4 + 3] = v.w;
  }
  __syncthreads();
  int kbase = (blockIdx.z ? D_MEM : 0) + k0;
#pragma unroll
  for (int i = 0; i < 4; ++i) {
    int idx = i * 256 + tid;
    int rr = idx >> 4;
    int c4 = (idx & 15) * 4;
    ushort4 o;
    o.x = f2b(t[(c4 + 0) * 65 + rr]);
    o.y = f2b(t[(c4 + 1) * 65 + rr]);
    o.z = f2b(t[(c4 + 2) * 65 + rr]);
    o.w = f2b(t[(c4 + 3) * 65 + rr]);
    *(ushort4*)(Bt + (size_t)(n0 + rr) * K_DIM + kbase + c4) = o;
  }
}

// ---------------------------------------------------------------------------
// Kernel 3: GEMM  G[m][n] = sum_k A[m][k] * Bt[n][k]   (bf16 in, bf16 out)
//
// 256x256 tile, BK=64, 8 waves (2M x 4N), 512 threads, 8-phase schedule
// (T3+T4 counted vmcnt + T5 setprio), per m201 template.
//
// LDS (128 KiB): As[buf][kh] 2x2x16KB at 0, Bs same at 65536.
//   A k-half region = [256 rows][4 chunks of 16B], row = 64B.
//   chunk (row, cpos) holds source k-chunk cpos ^ ((row^(row>>2))&3)
//   -> staging dest is linear (global_load_lds), source pre-swizzled;
//      frag ds_read_b128 lands 2 lanes/bank-slot = conflict-free.
//
// Phase (mh, ks) of tile t: MFMAs acc[mh*4..+3][0..3] += A(mh,ks) x B(ks).
//   ks0 halves dead after phase 1, ks1 after phase 3 -> staging skew:
//   p0: (t+1).A_k1   p1: (t+1).B_k1   p2: (t+2).A_k0   p3: (t+2).B_k0
//   (t+2 k0 regions write the CURRENT buffer, legal: dead since p1.)
// vmcnt(8) before the barriers ending p1 and p3: all but the 4 newest
// half-tiles (8 loads) have landed -> next phases' ds_reads are safe
// across all waves. Never drains to 0 in the main loop.
// Tail: staged source clamped to tile 63; target regions provably dead.
// ---------------------------------------------------------------------------
__device__ __forceinline__ void stage2(const ushort* g0, const ushort* g1,
                                       char* dst, int wave) {
  __builtin_amdgcn_global_load_lds((gas_t)g0, (las_t)(dst + wave * 1024), 16, 0, 0);
  __builtin_amdgcn_global_load_lds((gas_t)g1, (las_t)(dst + 8192 + wave * 1024), 16, 0, 0);
}

#define PHASE(MH, KS, BUF, G0, G1, LDST, DOVM)                                 \
  do {                                                                         \
    bf16x8 af[4];                                                              \
    {                                                                          \
      const char* ab_ = AsB + (BUF)*32768 + (KS)*16384;                        \
      _Pragma("unroll") for (int f_ = 0; f_ < 4; ++f_)                         \
          af[f_] = *(const bf16x8*)(ab_ + aoff[MH][f_]);                       \
      if ((MH) == 0) {                                                         \
        const char* bb_ = BsB + (BUF)*32768 + (KS)*16384;                      \
        _Pragma("unroll") for (int j_ = 0; j_ < 4; ++j_)                       \
            bfr[j_] = *(const bf16x8*)(bb_ + boff[j_]);                        \
      }                                                                        \
    }                                                                          \
    stage2((G0), (G1), (LDST), wave);                                          \
    __builtin_amdgcn_s_barrier();                                              \
    asm volatile("s_waitcnt lgkmcnt(0)" ::: "memory");                         \
    __builtin_amdgcn_sched_barrier(0);                                         \
    __builtin_amdgcn_s_setprio(1);                                             \
    _Pragma("unroll") for (int i_ = 0; i_ < 4; ++i_)                           \
        _Pragma("unroll") for (int j_ = 0; j_ < 4; ++j_)                       \
            acc[(MH)*4 + i_][j_] = __builtin_amdgcn_mfma_f32_16x16x32_bf16(    \
                af[i_], bfr[j_], acc[(MH)*4 + i_][j_], 0, 0, 0);               \
    __builtin_amdgcn_s_setprio(0);                                             \
    if (DOVM) asm volatile("s_waitcnt vmcnt(8)" ::: "memory");                 \
    __builtin_amdgcn_s_barrier();                                              \
  } while (0)

__global__ __launch_bounds__(512, 2) void gemm_bf16_kernel(
    const ushort* __restrict__ A,   // [M=4096][K=4096]
    const ushort* __restrict__ B,   // [N=8192][K=4096]
    ushort* __restrict__ C) {       // [M][N]
  __shared__ char smem[131072];
  char* AsB = smem;
  char* BsB = smem + 65536;
  const int K = K_DIM, N = N_DIM;

  int tid = threadIdx.x;
  int lane = tid & 63, wave = tid >> 6;
  int wm = wave >> 2, wn = wave & 3;      // 2 M-waves x 4 N-waves
  int q = lane >> 4, r = lane & 15;

  // XCD-aware swizzle: nwg=512 (divisible by 8). Each XCD chunk = 2 tile-rows,
  // so the 32 resident blocks per XCD share one 2MB A-panel in L2.
  int bid = blockIdx.x;
  int swz = (bid & 7) * 64 + (bid >> 3);
  int m0 = (swz >> 5) * 256;              // 16 tile rows
  int n0 = (swz & 31) * 256;              // 32 tile cols

  // staging sources (pre-swizzled): chunk ci = issue*512 + tid
  int ci0 = tid, ci1 = 512 + tid;
  int r0 = ci0 >> 2, c0 = (ci0 & 3) ^ ((r0 ^ (r0 >> 2)) & 3);
  int r1 = ci1 >> 2, c1 = (ci1 & 3) ^ ((r1 ^ (r1 >> 2)) & 3);
  const ushort* sA0 = A + (size_t)(m0 + r0) * K + c0 * 8;
  const ushort* sA1 = A + (size_t)(m0 + r1) * K + c1 * 8;
  const ushort* sB0 = B + (size_t)(n0 + r0) * K + c0 * 8;
  const ushort* sB1 = B + (size_t)(n0 + r1) * K + c1 * 8;

  // fragment byte offsets within a (buf, khalf) region
  int swzr = (r ^ (r >> 2)) & 3;
  int aoff[2][4], boff[4];
#pragma unroll
  for (int mh = 0; mh < 2; ++mh)
#pragma unroll
    for (int f = 0; f < 4; ++f) {
      int row = wm * 128 + mh * 64 + f * 16 + r;
      aoff[mh][f] = row * 64 + (q ^ swzr) * 16;
    }
#pragma unroll
  for (int j = 0; j < 4; ++j) {
    int col = wn * 64 + j * 16 + r;
    boff[j] = col * 64 + (q ^ swzr) * 16;
  }

  f32x4 acc[8][4];
#pragma unroll
  for (int i = 0; i < 8; ++i)
#pragma unroll
    for (int j = 0; j < 4; ++j) acc[i][j] = f32x4{0.f, 0.f, 0.f, 0.f};
  bf16x8 bfr[4];

  // prologue: tile0 {A_k0,B_k0,A_k1,B_k1}, tile1 {A_k0,B_k0} = 12 loads
  stage2(sA0,      sA1,      AsB + 0,     wave);   // (0).A_k0
  stage2(sB0,      sB1,      BsB + 0,     wave);   // (0).B_k0
  stage2(sA0 + 32, sA1 + 32, AsB + 16384, wave);   // (0).A_k1
  stage2(sB0 + 32, sB1 + 32, BsB + 16384, wave);   // (0).B_k1
  stage2(sA0 + 64, sA1 + 64, AsB + 32768, wave);   // (1).A_k0
  stage2(sB0 + 64, sB1 + 64, BsB + 32768, wave);   // (1).B_k0
  asm volatile("s_waitcnt vmcnt(8)" ::: "memory"); // (0).A_k0/B_k0 landed
  __builtin_amdgcn_s_barrier();

#pragma unroll 1
  for (int t = 0; t < 64; t += 2) {
    const int o1 = (t + 1) * 64;                       // always < 64*64
    const int o2 = (t + 2 < 64 ? t + 2 : 63) * 64;     // clamp at tail
    const int o3 = (t + 3 < 64 ? t + 3 : 63) * 64;
    // tile t (buf 0)
    PHASE(0, 0, 0, sA0 + o1 + 32, sA1 + o1 + 32, AsB + 49152, 0); // st (t+1).A_k1
    PHASE(1, 0, 0, sB0 + o1 + 32, sB1 + o1 + 32, BsB + 49152, 1); // st (t+1).B_k1
    PHASE(0, 1, 0, sA0 + o2,      sA1 + o2,      AsB + 0,     0); // st (t+2).A_k0
    PHASE(1, 1, 0, sB0 + o2,      sB1 + o2,      BsB + 0,     1); // st (t+2).B_k0
    // tile t+1 (buf 1)
    PHASE(0, 0, 1, sA0 + o2 + 32, sA1 + o2 + 32, AsB + 16384, 0); // st (t+2).A_k1
    PHASE(1, 0, 1, sB0 + o2 + 32, sB1 + o2 + 32, BsB + 16384, 1); // st (t+2).B_k1
    PHASE(0, 1, 1, sA0 + o3,      sA1 + o3,      AsB + 32768, 0); // st (t+3).A_k0
    PHASE(1, 1, 1, sB0 + o3,      sB1 + o3,      BsB + 32768, 1); // st (t+3).B_k0
  }

  // epilogue: C/D layout col=lane&15, row=(lane>>4)*4+reg
#pragma unroll
  for (int i = 0; i < 8; ++i) {
    int gm_base = m0 + wm * 128 + i * 16 + q * 4;
#pragma unroll
    for (int j = 0; j < 4; ++j) {
      int gn = n0 + wn * 64 + j * 16 + r;
      size_t base = (size_t)gm_base * N + gn;
#pragma unroll
      for (int e = 0; e < 4; ++e)
        C[base + (size_t)e * N] = f2b(acc[i][j][e]);
    }
  }
}

// ---------------------------------------------------------------------------
// Kernel 4: gating epilogue
// ---------------------------------------------------------------------------
__global__ void gate_kernel(const ushort* __restrict__ G,
                            const float* __restrict__ bl,
                            const float* __restrict__ br,
                            const float* __restrict__ lc,
                            const float* __restrict__ rc,
                            float* __restrict__ out) {
  int i4 = blockIdx.x * 256 + threadIdx.x;   // 4096*512 groups
  int row = i4 >> 9;
  int col = (i4 & 511) * 4;
  size_t gbase = (size_t)row * N_DIM + col;

  ushort4 ui = *(const ushort4*)(G + gbase);
  ushort4 uf = *(const ushort4*)(G + gbase + 1 * D_MEM);
  ushort4 ug = *(const ushort4*)(G + gbase + 2 * D_MEM);
  ushort4 uu = *(const ushort4*)(G + gbase + 3 * D_MEM);

  float4 bli = *(const float4*)(bl + col);
  float4 blf = *(const float4*)(bl + col + 1 * D_MEM);
  float4 blr = *(const float4*)(bl + col + 2 * D_MEM);
  float4 blu = *(const float4*)(bl + col + 3 * D_MEM);
  float4 bri = *(const float4*)(br + col);
  float4 brf = *(const float4*)(br + col + 1 * D_MEM);
  float4 brr = *(const float4*)(br + col + 2 * D_MEM);
  float4 bru = *(const float4*)(br + col + 3 * D_MEM);

  float4 vlc = *(const float4*)(lc + (size_t)row * D_MEM + col);
  float4 vrc = *(const float4*)(rc + (size_t)row * D_MEM + col);

  float4 vc, vh;
  {
    float gi = b2f(ui.x) + bli.x + bri.x;
    float gf = b2f(uf.x) + blf.x + brf.x;
    float gr = b2f(ug.x) + blr.x + brr.x;
    float gu = b2f(uu.x) + blu.x + bru.x;
    vc.x = sigm(gi) * tanh_fast(gu) + sigm(gf) * vlc.x + sigm(gr) * vrc.x;
    vh.x = tanh_fast(vc.x);
  }
  {
    float gi = b2f(ui.y) + bli.y + bri.y;
    float gf = b2f(uf.y) + blf.y + brf.y;
    float gr = b2f(ug.y) + blr.y + brr.y;
    float gu = b2f(uu.y) + blu.y + bru.y;
    vc.y = sigm(gi) * tanh_fast(gu) + sigm(gf) * vlc.y + sigm(gr) * vrc.y;
    vh.y = tanh_fast(vc.y);
  }
  {
    float gi = b2f(ui.z) + bli.z + bri.z;
    float gf = b2f(uf.z) + blf.z + brf.z;
    float gr = b2f(ug.z) + blr.z + brr.z;
    float gu = b2f(uu.z) + blu.z + bru.z;
    vc.z = sigm(gi) * tanh_fast(gu) + sigm(gf) * vlc.z + sigm(gr) * vrc.z;
    vh.z = tanh_fast(vc.z);
  }
  {
    float gi = b2f(ui.w) + bli.w + bri.w;
    float gf = b2f(uf.w) + blf.w + brf.w;
    float gr = b2f(ug.w) + blr.w + brr.w;
    float gu = b2f(uu.w) + blu.w + bru.w;
    vc.w = sigm(gi) * tanh_fast(gu) + sigm(gf) * vlc.w + sigm(gr) * vrc.w;
    vh.w = tanh_fast(vc.w);
  }

  size_t obase = (size_t)row * D_MEM + col;
  *(float4*)(out + obase) = vc;
  *(float4*)(out + (size_t)BATCH * D_MEM + obase) = vh;
}

// ---------------------------------------------------------------------------
extern "C" void kernel_launch(void* const* d_in, const int* in_sizes, int n_in,
                              void* d_out, int out_size, void* d_ws, size_t ws_size,
                              hipStream_t stream) {
  const float* lc = (const float*)d_in[0];
  const float* lh = (const float*)d_in[1];
  const float* rc = (const float*)d_in[2];
  const float* rh = (const float*)d_in[3];
  const float* Wl = (const float*)d_in[4];
  const float* bl = (const float*)d_in[5];
  const float* Wr = (const float*)d_in[6];
  const float* br = (const float*)d_in[7];
  float* out = (float*)d_out;

  char* ws = (char*)d_ws;
  ushort* A  = (ushort*)ws;                                // 32 MB  bf16 [4096][4096]
  ushort* Bt = (ushort*)(ws + (size_t)32 * 1024 * 1024);   // 64 MB  bf16 [8192][4096]
  ushort* G  = (ushort*)(ws + (size_t)96 * 1024 * 1024);   // 64 MB  bf16 [4096][8192]

  cast_concat_kernel<<<16384, 256, 0, stream>>>(lh, rh, A);
  dim3 tg(128, 32, 2);
  transpose_cast_kernel<<<tg, 256, 0, stream>>>(Wl, Wr, Bt);
  gemm_bf16_kernel<<<512, 512, 0, stream>>>(A, Bt, G);
  gate_kernel<<<8192, 256, 0, stream>>>(G, bl, br, lc, rc, out);
}

// Round 2
// 540.845 us; speedup vs baseline: 1.0107x; 1.0107x over previous
//
#include <hip/hip_runtime.h>
#include <stdint.h>

#define D_MEM 2048
#define BATCH 4096
#define K_DIM 4096   // 2*D
#define N_DIM 8192   // 4*D

typedef __bf16 bf16x8 __attribute__((ext_vector_type(8)));
typedef float f32x4 __attribute__((ext_vector_type(4)));

typedef const void __attribute__((address_space(1)))* gas_t;
typedef void __attribute__((address_space(3)))* las_t;

__device__ __forceinline__ ushort f2b(float f) {
  union { float f; uint32_t u; } v; v.f = f;
  uint32_t u = v.u + 0x7fffu + ((v.u >> 16) & 1u);
  return (ushort)(u >> 16);
}
__device__ __forceinline__ float b2f(ushort s) {
  union { uint32_t u; float f; } v; v.u = ((uint32_t)s) << 16;
  return v.f;
}
__device__ __forceinline__ float sigm(float x) {
  return 1.0f / (1.0f + __expf(-x));
}
__device__ __forceinline__ float tanh_fast(float x) {
  // tanh(x) = 2*sigmoid(2x) - 1 ; saturates correctly for |x| large
  return __builtin_fmaf(2.0f, sigm(2.0f * x), -1.0f);
}

// ---------------------------------------------------------------------------
// Kernel 1: cast+concat  A[m][k] = bf16( k<D ? lh[m][k] : rh[m][k-D] )
// ---------------------------------------------------------------------------
__global__ void cast_concat_kernel(const float* __restrict__ lh,
                                   const float* __restrict__ rh,
                                   ushort* __restrict__ A) {
  int i4 = blockIdx.x * 256 + threadIdx.x;     // 4096*1024 float4 groups
  int row = i4 >> 10;
  int col = (i4 & 1023) * 4;
  const float* src = (col < D_MEM) ? (lh + (size_t)row * D_MEM + col)
                                   : (rh + (size_t)row * D_MEM + (col - D_MEM));
  float4 v = *(const float4*)src;
  ushort4 o; o.x = f2b(v.x); o.y = f2b(v.y); o.z = f2b(v.z); o.w = f2b(v.w);
  *(ushort4*)(A + (size_t)row * K_DIM + col) = o;
}

// ---------------------------------------------------------------------------
// Kernel 2: transpose+cast  Bt[n][k] = bf16( W[k - koff][n] ),  W = Wl or Wr
// ---------------------------------------------------------------------------
__global__ void transpose_cast_kernel(const float* __restrict__ Wl,
                                      const float* __restrict__ Wr,
                                      ushort* __restrict__ Bt) {
  __shared__ float t[64 * 65];
  const float* W = blockIdx.z ? Wr : Wl;
  int n0 = blockIdx.x * 64;
  int k0 = blockIdx.y * 64;
  int tid = threadIdx.x;
#pragma unroll
  for (int i = 0; i < 4; ++i) {
    int idx = i * 256 + tid;
    int rr = idx >> 4;
    int c4 = (idx & 15) * 4;
    float4 v = *(const float4*)(W + (size_t)(k0 + rr) * N_DIM + n0 + c4);
    t[rr * 65 + c4 + 0] = v.x;
    t[rr * 65 + c4 + 1] = v.y;
    t[rr * 65 + c4 + 2] = v.z;
    t[rr * 65 + c4 + 3] = v.w;
  }
  __syncthreads();
  int kbase = (blockIdx.z ? D_MEM : 0) + k0;
#pragma unroll
  for (int i = 0; i < 4; ++i) {
    int idx = i * 256 + tid;
    int rr = idx >> 4;
    int c4 = (idx & 15) * 4;
    ushort4 o;
    o.x = f2b(t[(c4 + 0) * 65 + rr]);
    o.y = f2b(t[(c4 + 1) * 65 + rr]);
    o.z = f2b(t[(c4 + 2) * 65 + rr]);
    o.w = f2b(t[(c4 + 3) * 65 + rr]);
    *(ushort4*)(Bt + (size_t)(n0 + rr) * K_DIM + kbase + c4) = o;
  }
}

// ---------------------------------------------------------------------------
// Kernel 3: GEMM  G[m][n] = sum_k A[m][k] * Bt[n][k]   (bf16 in, bf16 out)
//
// 256x256 tile, BK=64, 8 waves (2M x 4N), 512 threads.
// Schedule v2: 2 halves per K-tile (one per k-half region), 2 barriers/tile.
// Per half: {issue 2 half-tile stages (4 global_load_lds) -> 12 ds_read_b128
// (A mh0, B, A mh1) -> 32 MFMA} with NO explicit lgkmcnt: the compiler's
// counted-lgkm scheduling overlaps the mh1 ds_reads with the mh0 MFMA
// cluster. vmcnt(8) before each barrier = 8 loads (2 half-tiles) in flight;
// everything older has landed, which is exactly what the next half reads.
//
// LDS (128 KiB): As[buf][kh] 2x2x16KB at 0, Bs same at 65536.
//   region = [256 rows][4 chunks of 16B]; chunk (row,cpos) holds source
//   chunk cpos ^ ((row^(row>>2))&3) -> linear DMA dest, pre-swizzled
//   source, conflict-free ds_read_b128 (8-lane groups cover all 8 quads).
//
// Staging skew per tile t (buf b): half0 stages (t+1).{A,B}_k1 -> buf b^1
// (dead since t-1's end barrier); half1 stages (t+2).{A,B}_k0 -> buf b
// (dead since this tile's mid barrier). Tail clamped to tile 63 (regions
// provably dead; duplicate writes carry identical data).
// ---------------------------------------------------------------------------
__device__ __forceinline__ void stage2(const ushort* g0, const ushort* g1,
                                       char* dst, int wave) {
  __builtin_amdgcn_global_load_lds((gas_t)g0, (las_t)(dst + wave * 1024), 16, 0, 0);
  __builtin_amdgcn_global_load_lds((gas_t)g1, (las_t)(dst + 8192 + wave * 1024), 16, 0, 0);
}

#define HALF(KS, BUF, GA0, GA1, DSTA, GB0, GB1, DSTB)                          \
  do {                                                                         \
    stage2((GA0), (GA1), (DSTA), wave);                                        \
    stage2((GB0), (GB1), (DSTB), wave);                                        \
    bf16x8 af0[4], af1[4], bq[4];                                              \
    const char* ab_ = AsB + (BUF)*32768 + (KS)*16384;                          \
    const char* bb_ = BsB + (BUF)*32768 + (KS)*16384;                          \
    _Pragma("unroll") for (int f_ = 0; f_ < 4; ++f_)                           \
        af0[f_] = *(const bf16x8*)(ab_ + aoff[0][f_]);                         \
    _Pragma("unroll") for (int j_ = 0; j_ < 4; ++j_)                           \
        bq[j_] = *(const bf16x8*)(bb_ + boff[j_]);                             \
    _Pragma("unroll") for (int f_ = 0; f_ < 4; ++f_)                           \
        af1[f_] = *(const bf16x8*)(ab_ + aoff[1][f_]);                         \
    __builtin_amdgcn_s_setprio(1);                                             \
    _Pragma("unroll") for (int i_ = 0; i_ < 4; ++i_)                           \
        _Pragma("unroll") for (int j_ = 0; j_ < 4; ++j_)                       \
            acc[i_][j_] = __builtin_amdgcn_mfma_f32_16x16x32_bf16(             \
                af0[i_], bq[j_], acc[i_][j_], 0, 0, 0);                        \
    _Pragma("unroll") for (int i_ = 0; i_ < 4; ++i_)                           \
        _Pragma("unroll") for (int j_ = 0; j_ < 4; ++j_)                       \
            acc[4 + i_][j_] = __builtin_amdgcn_mfma_f32_16x16x32_bf16(         \
                af1[i_], bq[j_], acc[4 + i_][j_], 0, 0, 0);                    \
    __builtin_amdgcn_s_setprio(0);                                             \
    asm volatile("s_waitcnt vmcnt(8)" ::: "memory");                           \
    __builtin_amdgcn_s_barrier();                                              \
  } while (0)

__global__ __launch_bounds__(512, 2) void gemm_bf16_kernel(
    const ushort* __restrict__ A,   // [M=4096][K=4096]
    const ushort* __restrict__ B,   // [N=8192][K=4096]
    ushort* __restrict__ C) {       // [M][N]
  __shared__ char smem[131072];
  char* AsB = smem;
  char* BsB = smem + 65536;
  const int K = K_DIM, N = N_DIM;

  int tid = threadIdx.x;
  int lane = tid & 63, wave = tid >> 6;
  int wm = wave >> 2, wn = wave & 3;      // 2 M-waves x 4 N-waves
  int q = lane >> 4, r = lane & 15;

  // XCD-aware swizzle: nwg=512 (divisible by 8). Each XCD chunk = 2 tile-rows,
  // so the 32 resident blocks per XCD share one 2MB A-panel in L2.
  int bid = blockIdx.x;
  int swz = (bid & 7) * 64 + (bid >> 3);
  int m0 = (swz >> 5) * 256;              // 16 tile rows
  int n0 = (swz & 31) * 256;              // 32 tile cols

  // staging sources (pre-swizzled): chunk ci = issue*512 + tid
  int ci0 = tid, ci1 = 512 + tid;
  int r0 = ci0 >> 2, c0 = (ci0 & 3) ^ ((r0 ^ (r0 >> 2)) & 3);
  int r1 = ci1 >> 2, c1 = (ci1 & 3) ^ ((r1 ^ (r1 >> 2)) & 3);
  const ushort* sA0 = A + (size_t)(m0 + r0) * K + c0 * 8;
  const ushort* sA1 = A + (size_t)(m0 + r1) * K + c1 * 8;
  const ushort* sB0 = B + (size_t)(n0 + r0) * K + c0 * 8;
  const ushort* sB1 = B + (size_t)(n0 + r1) * K + c1 * 8;

  // fragment byte offsets within a (buf, khalf) region
  int swzr = (r ^ (r >> 2)) & 3;
  int aoff[2][4], boff[4];
#pragma unroll
  for (int mh = 0; mh < 2; ++mh)
#pragma unroll
    for (int f = 0; f < 4; ++f) {
      int row = wm * 128 + mh * 64 + f * 16 + r;
      aoff[mh][f] = row * 64 + (q ^ swzr) * 16;
    }
#pragma unroll
  for (int j = 0; j < 4; ++j) {
    int col = wn * 64 + j * 16 + r;
    boff[j] = col * 64 + (q ^ swzr) * 16;
  }

  f32x4 acc[8][4];
#pragma unroll
  for (int i = 0; i < 8; ++i)
#pragma unroll
    for (int j = 0; j < 4; ++j) acc[i][j] = f32x4{0.f, 0.f, 0.f, 0.f};

  // prologue: tile0 {A_k0,B_k0,A_k1,B_k1}, tile1 {A_k0,B_k0} = 12 loads
  stage2(sA0,      sA1,      AsB + 0,     wave);   // (0).A_k0
  stage2(sB0,      sB1,      BsB + 0,     wave);   // (0).B_k0
  stage2(sA0 + 32, sA1 + 32, AsB + 16384, wave);   // (0).A_k1
  stage2(sB0 + 32, sB1 + 32, BsB + 16384, wave);   // (0).B_k1
  stage2(sA0 + 64, sA1 + 64, AsB + 32768, wave);   // (1).A_k0
  stage2(sB0 + 64, sB1 + 64, BsB + 32768, wave);   // (1).B_k0
  asm volatile("s_waitcnt vmcnt(8)" ::: "memory"); // (0).A_k0/B_k0 landed
  __builtin_amdgcn_s_barrier();

#pragma unroll 1
  for (int t = 0; t < 64; t += 2) {
    const int o1 = (t + 1) * 64;                       // always < 64*64
    const int o2 = (t + 2 < 64 ? t + 2 : 63) * 64;     // clamp at tail
    const int o3 = (t + 3 < 64 ? t + 3 : 63) * 64;
    // tile t (buf 0)
    HALF(0, 0, sA0 + o1 + 32, sA1 + o1 + 32, AsB + 49152,
               sB0 + o1 + 32, sB1 + o1 + 32, BsB + 49152); // st (t+1).k1
    HALF(1, 0, sA0 + o2,      sA1 + o2,      AsB + 0,
               sB0 + o2,      sB1 + o2,      BsB + 0);     // st (t+2).k0
    // tile t+1 (buf 1)
    HALF(0, 1, sA0 + o2 + 32, sA1 + o2 + 32, AsB + 16384,
               sB0 + o2 + 32, sB1 + o2 + 32, BsB + 16384); // st (t+2).k1
    HALF(1, 1, sA0 + o3,      sA1 + o3,      AsB + 32768,
               sB0 + o3,      sB1 + o3,      BsB + 32768); // st (t+3).k0
  }

  // epilogue: C/D layout col=lane&15, row=(lane>>4)*4+reg
#pragma unroll
  for (int i = 0; i < 8; ++i) {
    int gm_base = m0 + wm * 128 + i * 16 + q * 4;
#pragma unroll
    for (int j = 0; j < 4; ++j) {
      int gn = n0 + wn * 64 + j * 16 + r;
      size_t base = (size_t)gm_base * N + gn;
#pragma unroll
      for (int e = 0; e < 4; ++e)
        C[base + (size_t)e * N] = f2b(acc[i][j][e]);
    }
  }
}

// ---------------------------------------------------------------------------
// Kernel 4: gating epilogue
// ---------------------------------------------------------------------------
__global__ void gate_kernel(const ushort* __restrict__ G,
                            const float* __restrict__ bl,
                            const float* __restrict__ br,
                            const float* __restrict__ lc,
                            const float* __restrict__ rc,
                            float* __restrict__ out) {
  int i4 = blockIdx.x * 256 + threadIdx.x;   // 4096*512 groups
  int row = i4 >> 9;
  int col = (i4 & 511) * 4;
  size_t gbase = (size_t)row * N_DIM + col;

  ushort4 ui = *(const ushort4*)(G + gbase);
  ushort4 uf = *(const ushort4*)(G + gbase + 1 * D_MEM);
  ushort4 ug = *(const ushort4*)(G + gbase + 2 * D_MEM);
  ushort4 uu = *(const ushort4*)(G + gbase + 3 * D_MEM);

  float4 bli = *(const float4*)(bl + col);
  float4 blf = *(const float4*)(bl + col + 1 * D_MEM);
  float4 blr = *(const float4*)(bl + col + 2 * D_MEM);
  float4 blu = *(const float4*)(bl + col + 3 * D_MEM);
  float4 bri = *(const float4*)(br + col);
  float4 brf = *(const float4*)(br + col + 1 * D_MEM);
  float4 brr = *(const float4*)(br + col + 2 * D_MEM);
  float4 bru = *(const float4*)(br + col + 3 * D_MEM);

  float4 vlc = *(const float4*)(lc + (size_t)row * D_MEM + col);
  float4 vrc = *(const float4*)(rc + (size_t)row * D_MEM + col);

  float4 vc, vh;
  {
    float gi = b2f(ui.x) + bli.x + bri.x;
    float gf = b2f(uf.x) + blf.x + brf.x;
    float gr = b2f(ug.x) + blr.x + brr.x;
    float gu = b2f(uu.x) + blu.x + bru.x;
    vc.x = sigm(gi) * tanh_fast(gu) + sigm(gf) * vlc.x + sigm(gr) * vrc.x;
    vh.x = tanh_fast(vc.x);
  }
  {
    float gi = b2f(ui.y) + bli.y + bri.y;
    float gf = b2f(uf.y) + blf.y + brf.y;
    float gr = b2f(ug.y) + blr.y + brr.y;
    float gu = b2f(uu.y) + blu.y + bru.y;
    vc.y = sigm(gi) * tanh_fast(gu) + sigm(gf) * vlc.y + sigm(gr) * vrc.y;
    vh.y = tanh_fast(vc.y);
  }
  {
    float gi = b2f(ui.z) + bli.z + bri.z;
    float gf = b2f(uf.z) + blf.z + brf.z;
    float gr = b2f(ug.z) + blr.z + brr.z;
    float gu = b2f(uu.z) + blu.z + bru.z;
    vc.z = sigm(gi) * tanh_fast(gu) + sigm(gf) * vlc.z + sigm(gr) * vrc.z;
    vh.z = tanh_fast(vc.z);
  }
  {
    float gi = b2f(ui.w) + bli.w + bri.w;
    float gf = b2f(uf.w) + blf.w + brf.w;
    float gr = b2f(ug.w) + blr.w + brr.w;
    float gu = b2f(uu.w) + blu.w + bru.w;
    vc.w = sigm(gi) * tanh_fast(gu) + sigm(gf) * vlc.w + sigm(gr) * vrc.w;
    vh.w = tanh_fast(vc.w);
  }

  size_t obase = (size_t)row * D_MEM + col;
  *(float4*)(out + obase) = vc;
  *(float4*)(out + (size_t)BATCH * D_MEM + obase) = vh;
}

// ---------------------------------------------------------------------------
extern "C" void kernel_launch(void* const* d_in, const int* in_sizes, int n_in,
                              void* d_out, int out_size, void* d_ws, size_t ws_size,
                              hipStream_t stream) {
  const float* lc = (const float*)d_in[0];
  const float* lh = (const float*)d_in[1];
  const float* rc = (const float*)d_in[2];
  const float* rh = (const float*)d_in[3];
  const float* Wl = (const float*)d_in[4];
  const float* bl = (const float*)d_in[5];
  const float* Wr = (const float*)d_in[6];
  const float* br = (const float*)d_in[7];
  float* out = (float*)d_out;

  char* ws = (char*)d_ws;
  ushort* A  = (ushort*)ws;                                // 32 MB  bf16 [4096][4096]
  ushort* Bt = (ushort*)(ws + (size_t)32 * 1024 * 1024);   // 64 MB  bf16 [8192][4096]
  ushort* G  = (ushort*)(ws + (size_t)96 * 1024 * 1024);   // 64 MB  bf16 [4096][8192]

  cast_concat_kernel<<<16384, 256, 0, stream>>>(lh, rh, A);
  dim3 tg(128, 32, 2);
  transpose_cast_kernel<<<tg, 256, 0, stream>>>(Wl, Wr, Bt);
  gemm_bf16_kernel<<<512, 512, 0, stream>>>(A, Bt, G);
  gate_kernel<<<8192, 256, 0, stream>>>(G, bl, br, lc, rc, out);
}

// Round 3
// 535.930 us; speedup vs baseline: 1.0199x; 1.0092x over previous
//
#include <hip/hip_runtime.h>
#include <stdint.h>

#define D_MEM 2048
#define BATCH 4096
#define K_DIM 4096   // 2*D
#define N_DIM 8192   // 4*D

typedef __bf16 bf16x8 __attribute__((ext_vector_type(8)));
typedef float f32x4 __attribute__((ext_vector_type(4)));

typedef const void __attribute__((address_space(1)))* gas_t;
typedef void __attribute__((address_space(3)))* las_t;

__device__ __forceinline__ ushort f2b(float f) {
  union { float f; uint32_t u; } v; v.f = f;
  uint32_t u = v.u + 0x7fffu + ((v.u >> 16) & 1u);
  return (ushort)(u >> 16);
}
__device__ __forceinline__ float b2f(ushort s) {
  union { uint32_t u; float f; } v; v.u = ((uint32_t)s) << 16;
  return v.f;
}
__device__ __forceinline__ float sigm(float x) {
  return 1.0f / (1.0f + __expf(-x));
}
__device__ __forceinline__ float tanh_fast(float x) {
  // tanh(x) = 2*sigmoid(2x) - 1 ; saturates correctly for |x| large
  return __builtin_fmaf(2.0f, sigm(2.0f * x), -1.0f);
}

// ---------------------------------------------------------------------------
// Kernel 1: cast+concat  A[m][k] = bf16( k<D ? lh[m][k] : rh[m][k-D] )
// ---------------------------------------------------------------------------
__global__ void cast_concat_kernel(const float* __restrict__ lh,
                                   const float* __restrict__ rh,
                                   ushort* __restrict__ A) {
  int i4 = blockIdx.x * 256 + threadIdx.x;     // 4096*1024 float4 groups
  int row = i4 >> 10;
  int col = (i4 & 1023) * 4;
  const float* src = (col < D_MEM) ? (lh + (size_t)row * D_MEM + col)
                                   : (rh + (size_t)row * D_MEM + (col - D_MEM));
  float4 v = *(const float4*)src;
  ushort4 o; o.x = f2b(v.x); o.y = f2b(v.y); o.z = f2b(v.z); o.w = f2b(v.w);
  *(ushort4*)(A + (size_t)row * K_DIM + col) = o;
}

// ---------------------------------------------------------------------------
// Kernel 2: transpose+cast  Bt[n][k] = bf16( W[k - koff][n] ),  W = Wl or Wr
// ---------------------------------------------------------------------------
__global__ void transpose_cast_kernel(const float* __restrict__ Wl,
                                      const float* __restrict__ Wr,
                                      ushort* __restrict__ Bt) {
  __shared__ float t[64 * 65];
  const float* W = blockIdx.z ? Wr : Wl;
  int n0 = blockIdx.x * 64;
  int k0 = blockIdx.y * 64;
  int tid = threadIdx.x;
#pragma unroll
  for (int i = 0; i < 4; ++i) {
    int idx = i * 256 + tid;
    int rr = idx >> 4;
    int c4 = (idx & 15) * 4;
    float4 v = *(const float4*)(W + (size_t)(k0 + rr) * N_DIM + n0 + c4);
    t[rr * 65 + c4 + 0] = v.x;
    t[rr * 65 + c4 + 1] = v.y;
    t[rr * 65 + c4 + 2] = v.z;
    t[rr * 65 + c4 + 3] = v.w;
  }
  __syncthreads();
  int kbase = (blockIdx.z ? D_MEM : 0) + k0;
#pragma unroll
  for (int i = 0; i < 4; ++i) {
    int idx = i * 256 + tid;
    int rr = idx >> 4;
    int c4 = (idx & 15) * 4;
    ushort4 o;
    o.x = f2b(t[(c4 + 0) * 65 + rr]);
    o.y = f2b(t[(c4 + 1) * 65 + rr]);
    o.z = f2b(t[(c4 + 2) * 65 + rr]);
    o.w = f2b(t[(c4 + 3) * 65 + rr]);
    *(ushort4*)(Bt + (size_t)(n0 + rr) * K_DIM + kbase + c4) = o;
  }
}

// ---------------------------------------------------------------------------
// Kernel 3: GEMM + fused gating.
//
// Same main loop as round 2 (256x256 tile, BK=64, 8 waves 2Mx4N, 2 halves
// per K-tile, counted vmcnt(8), chunk-XOR LDS swizzle). NEW: the block's
// 256-wide N-span is remapped to [4 gates][64 d]: B-tile row srow in 0..255
// maps to global n = (srow>>6)*2048 + d0 + (srow&63), and b-fragment j reads
// LDS rows j*64 + wn*16 + r  -> fragment index j IS the gate index, and each
// lane's acc[i][0..3][e] holds {i, lf, rf, u} for the SAME (m, d).
// The swizzle terms (row&3, (row>>2)&3) depend only on r -> main loop
// addressing is unchanged. Epilogue applies the gating in-register and
// writes c,h fp32 directly; the separate gate kernel and the G workspace
// round-trip (128 MB HBM) are eliminated.
// ---------------------------------------------------------------------------
__device__ __forceinline__ void stage2(const ushort* g0, const ushort* g1,
                                       char* dst, int wave) {
  __builtin_amdgcn_global_load_lds((gas_t)g0, (las_t)(dst + wave * 1024), 16, 0, 0);
  __builtin_amdgcn_global_load_lds((gas_t)g1, (las_t)(dst + 8192 + wave * 1024), 16, 0, 0);
}

#define HALF(KS, BUF, GA0, GA1, DSTA, GB0, GB1, DSTB)                          \
  do {                                                                         \
    stage2((GA0), (GA1), (DSTA), wave);                                        \
    stage2((GB0), (GB1), (DSTB), wave);                                        \
    bf16x8 af0[4], af1[4], bq[4];                                              \
    const char* ab_ = AsB + (BUF)*32768 + (KS)*16384;                          \
    const char* bb_ = BsB + (BUF)*32768 + (KS)*16384;                          \
    _Pragma("unroll") for (int f_ = 0; f_ < 4; ++f_)                           \
        af0[f_] = *(const bf16x8*)(ab_ + aoff[0][f_]);                         \
    _Pragma("unroll") for (int j_ = 0; j_ < 4; ++j_)                           \
        bq[j_] = *(const bf16x8*)(bb_ + boff[j_]);                             \
    _Pragma("unroll") for (int f_ = 0; f_ < 4; ++f_)                           \
        af1[f_] = *(const bf16x8*)(ab_ + aoff[1][f_]);                         \
    __builtin_amdgcn_s_setprio(1);                                             \
    _Pragma("unroll") for (int i_ = 0; i_ < 4; ++i_)                           \
        _Pragma("unroll") for (int j_ = 0; j_ < 4; ++j_)                       \
            acc[i_][j_] = __builtin_amdgcn_mfma_f32_16x16x32_bf16(             \
                af0[i_], bq[j_], acc[i_][j_], 0, 0, 0);                        \
    _Pragma("unroll") for (int i_ = 0; i_ < 4; ++i_)                           \
        _Pragma("unroll") for (int j_ = 0; j_ < 4; ++j_)                       \
            acc[4 + i_][j_] = __builtin_amdgcn_mfma_f32_16x16x32_bf16(         \
                af1[i_], bq[j_], acc[4 + i_][j_], 0, 0, 0);                    \
    __builtin_amdgcn_s_setprio(0);                                             \
    asm volatile("s_waitcnt vmcnt(8)" ::: "memory");                           \
    __builtin_amdgcn_s_barrier();                                              \
  } while (0)

__global__ __launch_bounds__(512, 2) void gemm_bf16_kernel(
    const ushort* __restrict__ A,   // [M=4096][K=4096]
    const ushort* __restrict__ B,   // [N=8192][K=4096]
    const float* __restrict__ bl,   // [8192]
    const float* __restrict__ br,   // [8192]
    const float* __restrict__ lc,   // [4096][2048]
    const float* __restrict__ rc,   // [4096][2048]
    float* __restrict__ out) {      // [2][4096][2048]
  __shared__ char smem[131072];
  char* AsB = smem;
  char* BsB = smem + 65536;
  const int K = K_DIM;

  int tid = threadIdx.x;
  int lane = tid & 63, wave = tid >> 6;
  int wm = wave >> 2, wn = wave & 3;      // 2 M-waves x 4 N-waves
  int q = lane >> 4, r = lane & 15;

  // XCD-aware swizzle: nwg=512 (divisible by 8).
  int bid = blockIdx.x;
  int swz = (bid & 7) * 64 + (bid >> 3);
  int m0 = (swz >> 5) * 256;              // 16 tile rows (m)
  int d0 = (swz & 31) * 64;               // 32 tile cols (d-blocks of 64)

  // staging sources (pre-swizzled): chunk ci = issue*512 + tid
  int ci0 = tid, ci1 = 512 + tid;
  int r0 = ci0 >> 2, c0 = (ci0 & 3) ^ ((r0 ^ (r0 >> 2)) & 3);
  int r1 = ci1 >> 2, c1 = (ci1 & 3) ^ ((r1 ^ (r1 >> 2)) & 3);
  // B rows remapped: srow -> gate (srow>>6), d-local (srow&63)
  int nb0 = (r0 >> 6) * D_MEM + d0 + (r0 & 63);
  int nb1 = (r1 >> 6) * D_MEM + d0 + (r1 & 63);
  const ushort* sA0 = A + (size_t)(m0 + r0) * K + c0 * 8;
  const ushort* sA1 = A + (size_t)(m0 + r1) * K + c1 * 8;
  const ushort* sB0 = B + (size_t)nb0 * K + c0 * 8;
  const ushort* sB1 = B + (size_t)nb1 * K + c1 * 8;

  // fragment byte offsets within a (buf, khalf) region
  int swzr = (r ^ (r >> 2)) & 3;
  int aoff[2][4], boff[4];
#pragma unroll
  for (int mh = 0; mh < 2; ++mh)
#pragma unroll
    for (int f = 0; f < 4; ++f) {
      int row = wm * 128 + mh * 64 + f * 16 + r;
      aoff[mh][f] = row * 64 + (q ^ swzr) * 16;
    }
#pragma unroll
  for (int j = 0; j < 4; ++j) {
    int row = j * 64 + wn * 16 + r;       // gate j, d-local wn*16+r
    boff[j] = row * 64 + (q ^ swzr) * 16;
  }

  f32x4 acc[8][4];
#pragma unroll
  for (int i = 0; i < 8; ++i)
#pragma unroll
    for (int j = 0; j < 4; ++j) acc[i][j] = f32x4{0.f, 0.f, 0.f, 0.f};

  // prologue: tile0 {A_k0,B_k0,A_k1,B_k1}, tile1 {A_k0,B_k0} = 12 loads
  stage2(sA0,      sA1,      AsB + 0,     wave);   // (0).A_k0
  stage2(sB0,      sB1,      BsB + 0,     wave);   // (0).B_k0
  stage2(sA0 + 32, sA1 + 32, AsB + 16384, wave);   // (0).A_k1
  stage2(sB0 + 32, sB1 + 32, BsB + 16384, wave);   // (0).B_k1
  stage2(sA0 + 64, sA1 + 64, AsB + 32768, wave);   // (1).A_k0
  stage2(sB0 + 64, sB1 + 64, BsB + 32768, wave);   // (1).B_k0
  asm volatile("s_waitcnt vmcnt(8)" ::: "memory"); // (0).A_k0/B_k0 landed
  __builtin_amdgcn_s_barrier();

#pragma unroll 1
  for (int t = 0; t < 64; t += 2) {
    const int o1 = (t + 1) * 64;                       // always < 64*64
    const int o2 = (t + 2 < 64 ? t + 2 : 63) * 64;     // clamp at tail
    const int o3 = (t + 3 < 64 ? t + 3 : 63) * 64;
    // tile t (buf 0)
    HALF(0, 0, sA0 + o1 + 32, sA1 + o1 + 32, AsB + 49152,
               sB0 + o1 + 32, sB1 + o1 + 32, BsB + 49152); // st (t+1).k1
    HALF(1, 0, sA0 + o2,      sA1 + o2,      AsB + 0,
               sB0 + o2,      sB1 + o2,      BsB + 0);     // st (t+2).k0
    // tile t+1 (buf 1)
    HALF(0, 1, sA0 + o2 + 32, sA1 + o2 + 32, AsB + 16384,
               sB0 + o2 + 32, sB1 + o2 + 32, BsB + 16384); // st (t+2).k1
    HALF(1, 1, sA0 + o3,      sA1 + o3,      AsB + 32768,
               sB0 + o3,      sB1 + o3,      BsB + 32768); // st (t+3).k0
  }

  // -------- fused gating epilogue --------
  // Lane owns d = d0 + wn*16 + r (fixed). acc[i][j][e]: gate j at
  // m = m0 + wm*128 + i*16 + q*4 + e.
  int d = d0 + wn * 16 + r;
  float bs0 = bl[0 * D_MEM + d] + br[0 * D_MEM + d];   // input gate bias
  float bs1 = bl[1 * D_MEM + d] + br[1 * D_MEM + d];   // left forget
  float bs2 = bl[2 * D_MEM + d] + br[2 * D_MEM + d];   // right forget
  float bs3 = bl[3 * D_MEM + d] + br[3 * D_MEM + d];   // update
  float* outc = out + d;
  float* outh = out + (size_t)BATCH * D_MEM + d;

#pragma unroll
  for (int i = 0; i < 8; ++i) {
    int mb = m0 + wm * 128 + i * 16 + q * 4;
#pragma unroll
    for (int e = 0; e < 4; ++e) {
      size_t mrow = (size_t)(mb + e) * D_MEM;
      float gi = acc[i][0][e] + bs0;
      float gf = acc[i][1][e] + bs1;
      float gr = acc[i][2][e] + bs2;
      float gu = acc[i][3][e] + bs3;
      float c = sigm(gi) * tanh_fast(gu) + sigm(gf) * lc[mrow + d] +
                sigm(gr) * rc[mrow + d];
      outc[mrow] = c;
      outh[mrow] = tanh_fast(c);
    }
  }
}

// ---------------------------------------------------------------------------
extern "C" void kernel_launch(void* const* d_in, const int* in_sizes, int n_in,
                              void* d_out, int out_size, void* d_ws, size_t ws_size,
                              hipStream_t stream) {
  const float* lc = (const float*)d_in[0];
  const float* lh = (const float*)d_in[1];
  const float* rc = (const float*)d_in[2];
  const float* rh = (const float*)d_in[3];
  const float* Wl = (const float*)d_in[4];
  const float* bl = (const float*)d_in[5];
  const float* Wr = (const float*)d_in[6];
  const float* br = (const float*)d_in[7];
  float* out = (float*)d_out;

  char* ws = (char*)d_ws;
  ushort* A  = (ushort*)ws;                                // 32 MB  bf16 [4096][4096]
  ushort* Bt = (ushort*)(ws + (size_t)32 * 1024 * 1024);   // 64 MB  bf16 [8192][4096]

  cast_concat_kernel<<<16384, 256, 0, stream>>>(lh, rh, A);
  dim3 tg(128, 32, 2);
  transpose_cast_kernel<<<tg, 256, 0, stream>>>(Wl, Wr, Bt);
  gemm_bf16_kernel<<<512, 512, 0, stream>>>(A, Bt, bl, br, lc, rc, out);
}

// Round 5
// 524.365 us; speedup vs baseline: 1.0424x; 1.0221x over previous
//
#include <hip/hip_runtime.h>
#include <stdint.h>

#define D_MEM 2048
#define BATCH 4096
#define K_DIM 4096   // 2*D
#define N_DIM 8192   // 4*D

typedef __bf16 bf16x8 __attribute__((ext_vector_type(8)));
typedef float f32x4 __attribute__((ext_vector_type(4)));

typedef const void __attribute__((address_space(1)))* gas_t;
typedef void __attribute__((address_space(3)))* las_t;

__device__ __forceinline__ ushort f2b(float f) {
  union { float f; uint32_t u; } v; v.f = f;
  uint32_t u = v.u + 0x7fffu + ((v.u >> 16) & 1u);
  return (ushort)(u >> 16);
}
__device__ __forceinline__ float b2f(ushort s) {
  union { uint32_t u; float f; } v; v.u = ((uint32_t)s) << 16;
  return v.f;
}
__device__ __forceinline__ float sigm(float x) {
  return 1.0f / (1.0f + __expf(-x));
}
__device__ __forceinline__ float tanh_fast(float x) {
  return __builtin_fmaf(2.0f, sigm(2.0f * x), -1.0f);
}

// ---------------------------------------------------------------------------
// Kernel 1: cast+concat  A[m][k] = bf16( k<D ? lh[m][k] : rh[m][k-D] )
// ---------------------------------------------------------------------------
__global__ void cast_concat_kernel(const float* __restrict__ lh,
                                   const float* __restrict__ rh,
                                   ushort* __restrict__ A) {
  int i4 = blockIdx.x * 256 + threadIdx.x;     // 4096*1024 float4 groups
  int row = i4 >> 10;
  int col = (i4 & 1023) * 4;
  const float* src = (col < D_MEM) ? (lh + (size_t)row * D_MEM + col)
                                   : (rh + (size_t)row * D_MEM + (col - D_MEM));
  float4 v = *(const float4*)src;
  ushort4 o; o.x = f2b(v.x); o.y = f2b(v.y); o.z = f2b(v.z); o.w = f2b(v.w);
  *(ushort4*)(A + (size_t)row * K_DIM + col) = o;
}

// ---------------------------------------------------------------------------
// Kernel 2: transpose+cast with gate-interleaved row remap.
// Bt2 row n' = (d>>4)*64 + gate*16 + (d&15), where n = gate*2048 + d is the
// original W column. This puts, for each 64-d block, the 4 gates at stride 16
// inside a 64-row group -> each GEMM wave's 4 b-fragments are the 4 gates of
// its own d (fused gating stays lane-local).
// ---------------------------------------------------------------------------
__global__ void transpose_cast_kernel(const float* __restrict__ Wl,
                                      const float* __restrict__ Wr,
                                      ushort* __restrict__ Bt) {
  __shared__ float t[64 * 65];
  const float* W = blockIdx.z ? Wr : Wl;
  int n0 = blockIdx.x * 64;
  int k0 = blockIdx.y * 64;
  int tid = threadIdx.x;
#pragma unroll
  for (int i = 0; i < 4; ++i) {
    int idx = i * 256 + tid;
    int rr = idx >> 4;
    int c4 = (idx & 15) * 4;
    float4 v = *(const float4*)(W + (size_t)(k0 + rr) * N_DIM + n0 + c4);
    t[rr * 65 + c4 + 0] = v.x;
    t[rr * 65 + c4 + 1] = v.y;
    t[rr * 65 + c4 + 2] = v.z;
    t[rr * 65 + c4 + 3] = v.w;
  }
  __syncthreads();
  int kbase = (blockIdx.z ? D_MEM : 0) + k0;
#pragma unroll
  for (int i = 0; i < 4; ++i) {
    int idx = i * 256 + tid;
    int rr = idx >> 4;            // n-local row 0..63
    int c4 = (idx & 15) * 4;      // k-local col
    ushort4 o;
    o.x = f2b(t[(c4 + 0) * 65 + rr]);
    o.y = f2b(t[(c4 + 1) * 65 + rr]);
    o.z = f2b(t[(c4 + 2) * 65 + rr]);
    o.w = f2b(t[(c4 + 3) * 65 + rr]);
    int n = n0 + rr;
    int d = n & (D_MEM - 1);
    int g = n >> 11;
    int nrow = ((d >> 4) << 6) + (g << 4) + (d & 15);
    *(ushort4*)(Bt + (size_t)nrow * K_DIM + kbase + c4) = o;
  }
}

// ---------------------------------------------------------------------------
// Kernel 3: GEMM + fused gating. 256x256 tile, BK=64, 16 waves (4Mx4N),
// 1024 threads, 4 waves/SIMD — occupancy fix vs r3 (2 waves/SIMD summed the
// {MFMA, LDS-read, DMA} pipes; 4 waves/SIMD lets them overlap).
//
// LDS: 4 rotating 16KB k32-regions per operand (A at 0, B at 65536).
// Region = [256 rows][64 B]; chunk (row,c') holds source chunk
// c' ^ ((row^(row>>2))&3): linear DMA dest, pre-swizzled source,
// conflict-free ds_read_b128.
// Schedule: half h reads region h&3, stages region (h+3)&3 (1 gload A +
// 1 gload B per thread), vmcnt(4) + barrier per half (2 halves in flight).
// B panel rows are gate-interleaved (see kernel 2): b-frag j = gate j at
// d = d0 + wn*16 + r -> in-register gating epilogue.
// ---------------------------------------------------------------------------
__global__ __launch_bounds__(1024, 4) void gemm_bf16_kernel(
    const ushort* __restrict__ A,   // [M=4096][K=4096]
    const ushort* __restrict__ B,   // [8192][K] gate-interleaved rows
    const float* __restrict__ bl,   // [8192]
    const float* __restrict__ br,   // [8192]
    const float* __restrict__ lc,   // [4096][2048]
    const float* __restrict__ rc,   // [4096][2048]
    float* __restrict__ out) {      // [2][4096][2048]
  __shared__ char smem[131072];
  char* AsB = smem;
  char* BsB = smem + 65536;
  const int K = K_DIM;

  int tid = threadIdx.x;
  int lane = tid & 63, wave = tid >> 6;
  int wm = wave >> 2, wn = wave & 3;      // 4 M-waves x 4 N-waves
  int q = lane >> 4, r = lane & 15;

  // XCD-aware swizzle: nwg=512 (divisible by 8).
  int bid = blockIdx.x;
  int swz = (bid & 7) * 64 + (bid >> 3);
  int m0 = (swz >> 5) * 256;              // 16 tile rows (m)
  int d0 = (swz & 31) * 64;               // 32 tile cols (d-blocks of 64)

  // staging source (pre-swizzled): chunk ci = tid; row=ci>>2, cpos=ci&3
  int sr = tid >> 2, sc = (tid & 3) ^ ((sr ^ (sr >> 2)) & 3);
  const ushort* sA0 = A + (size_t)(m0 + sr) * K + sc * 8;
  const ushort* sB0 = B + (size_t)(d0 * 4 + sr) * K + sc * 8;

  // fragment byte offsets within a 16KB region
  int swzr = (r ^ (r >> 2)) & 3;
  int aoff[4], boff[4];
#pragma unroll
  for (int f = 0; f < 4; ++f) {
    int row = wm * 64 + f * 16 + r;
    aoff[f] = row * 64 + (q ^ swzr) * 16;
  }
#pragma unroll
  for (int j = 0; j < 4; ++j) {
    int row = wn * 64 + j * 16 + r;       // gate j, d-local wn*16+r
    boff[j] = row * 64 + (q ^ ((row ^ (row >> 2)) & 3)) * 16;
  }

  f32x4 acc[4][4];
#pragma unroll
  for (int i = 0; i < 4; ++i)
#pragma unroll
    for (int j = 0; j < 4; ++j) acc[i][j] = f32x4{0.f, 0.f, 0.f, 0.f};

  int wb = wave * 1024;   // per-wave linear DMA slot within a region

  // prologue: stage halves 0,1,2 into regions 0,1,2
  __builtin_amdgcn_global_load_lds((gas_t)(sA0 +  0), (las_t)(AsB + 0     + wb), 16, 0, 0);
  __builtin_amdgcn_global_load_lds((gas_t)(sB0 +  0), (las_t)(BsB + 0     + wb), 16, 0, 0);
  __builtin_amdgcn_global_load_lds((gas_t)(sA0 + 32), (las_t)(AsB + 16384 + wb), 16, 0, 0);
  __builtin_amdgcn_global_load_lds((gas_t)(sB0 + 32), (las_t)(BsB + 16384 + wb), 16, 0, 0);
  __builtin_amdgcn_global_load_lds((gas_t)(sA0 + 64), (las_t)(AsB + 32768 + wb), 16, 0, 0);
  __builtin_amdgcn_global_load_lds((gas_t)(sB0 + 64), (las_t)(BsB + 32768 + wb), 16, 0, 0);
  asm volatile("s_waitcnt vmcnt(4)" ::: "memory");  // half 0 landed
  __builtin_amdgcn_s_barrier();

#define HALF(P)                                                                \
  do {                                                                         \
    const int h_ = t2 + (P);                                                   \
    const int rgn_ = (h_ & 3) * 16384;                                         \
    const int sr_ = ((h_ + 3) & 3) * 16384;                                    \
    const int so_ = (h_ + 3 < 128 ? h_ + 3 : 127) * 32;                        \
    __builtin_amdgcn_global_load_lds((gas_t)(sA0 + so_),                       \
                                     (las_t)(AsB + sr_ + wb), 16, 0, 0);       \
    __builtin_amdgcn_global_load_lds((gas_t)(sB0 + so_),                       \
                                     (las_t)(BsB + sr_ + wb), 16, 0, 0);       \
    bf16x8 af[4], bq[4];                                                       \
    const char* ab_ = AsB + rgn_;                                              \
    const char* bb_ = BsB + rgn_;                                              \
    _Pragma("unroll") for (int f_ = 0; f_ < 4; ++f_)                           \
        af[f_] = *(const bf16x8*)(ab_ + aoff[f_]);                             \
    _Pragma("unroll") for (int j_ = 0; j_ < 4; ++j_)                           \
        bq[j_] = *(const bf16x8*)(bb_ + boff[j_]);                             \
    __builtin_amdgcn_s_setprio(1);                                             \
    _Pragma("unroll") for (int i_ = 0; i_ < 4; ++i_)                           \
        _Pragma("unroll") for (int j_ = 0; j_ < 4; ++j_)                       \
            acc[i_][j_] = __builtin_amdgcn_mfma_f32_16x16x32_bf16(             \
                af[i_], bq[j_], acc[i_][j_], 0, 0, 0);                         \
    __builtin_amdgcn_s_setprio(0);                                             \
    asm volatile("s_waitcnt vmcnt(4)" ::: "memory");                           \
    __builtin_amdgcn_s_barrier();                                              \
  } while (0)

#pragma unroll 1
  for (int t2 = 0; t2 < 128; t2 += 4) {
    HALF(0);
    HALF(1);
    HALF(2);
    HALF(3);
  }
#undef HALF

  // -------- fused gating epilogue --------
  // Lane owns d = d0 + wn*16 + r. acc[i][j][e]: gate j at
  // m = m0 + wm*64 + i*16 + q*4 + e.
  int d = d0 + wn * 16 + r;
  float bs0 = bl[0 * D_MEM + d] + br[0 * D_MEM + d];
  float bs1 = bl[1 * D_MEM + d] + br[1 * D_MEM + d];
  float bs2 = bl[2 * D_MEM + d] + br[2 * D_MEM + d];
  float bs3 = bl[3 * D_MEM + d] + br[3 * D_MEM + d];
  float* outc = out + d;
  float* outh = out + (size_t)BATCH * D_MEM + d;

#pragma unroll
  for (int i = 0; i < 4; ++i) {
    int mb = m0 + wm * 64 + i * 16 + q * 4;
#pragma unroll
    for (int e = 0; e < 4; ++e) {
      size_t mrow = (size_t)(mb + e) * D_MEM;
      float gi = acc[i][0][e] + bs0;
      float gf = acc[i][1][e] + bs1;
      float gr = acc[i][2][e] + bs2;
      float gu = acc[i][3][e] + bs3;
      float c = sigm(gi) * tanh_fast(gu) + sigm(gf) * lc[mrow + d] +
                sigm(gr) * rc[mrow + d];
      outc[mrow] = c;
      outh[mrow] = tanh_fast(c);
    }
  }
}

// ---------------------------------------------------------------------------
extern "C" void kernel_launch(void* const* d_in, const int* in_sizes, int n_in,
                              void* d_out, int out_size, void* d_ws, size_t ws_size,
                              hipStream_t stream) {
  const float* lc = (const float*)d_in[0];
  const float* lh = (const float*)d_in[1];
  const float* rc = (const float*)d_in[2];
  const float* rh = (const float*)d_in[3];
  const float* Wl = (const float*)d_in[4];
  const float* bl = (const float*)d_in[5];
  const float* Wr = (const float*)d_in[6];
  const float* br = (const float*)d_in[7];
  float* out = (float*)d_out;

  char* ws = (char*)d_ws;
  ushort* A  = (ushort*)ws;                                // 32 MB  bf16 [4096][4096]
  ushort* Bt = (ushort*)(ws + (size_t)32 * 1024 * 1024);   // 64 MB  bf16 [8192][4096]

  cast_concat_kernel<<<16384, 256, 0, stream>>>(lh, rh, A);
  dim3 tg(128, 32, 2);
  transpose_cast_kernel<<<tg, 256, 0, stream>>>(Wl, Wr, Bt);
  gemm_bf16_kernel<<<512, 1024, 0, stream>>>(A, Bt, bl, br, lc, rc, out);
}